// Round 2
// baseline (1428.068 us; speedup 1.0000x reference)
//
#include <hip/hip_runtime.h>
#include <math.h>

// ---------------- workspace layout (floats) ----------------
#define OFF_Y2   0
#define OFF_QKV  17981440
#define OFF_ST   (17981440 + 5971968)
// stats offsets
#define ST_SX   0
#define ST_SXX  22
#define ST_WF   506
#define ST_BF   990
#define ST_Y2S  1012
#define ST_Y2Q  1032
#define ST_TOT  1052

#define LOGEPS -9.210340371976182f
#define NSWEEP 5   // 4 sweeps FAILED: absmax 2.29e-2 > 1.91e-2 thr (r7). 5 -> 3.9e-3.
#define SHIFT  12.0f   // mixed eigenvalues in [-11.62, ~1e-4] -> shifted PSD

// ---------------- K0: zero stats ----------------
__global__ __launch_bounds__(256) void k0_zero(float* __restrict__ st){
  for (int i = threadIdx.x; i < ST_TOT; i += 256) st[i] = 0.f;
}

// ---------------- K1: x second moments (for closed-form BN1 stats) ----------------
__global__ __launch_bounds__(256) void k1_xstats(const float* __restrict__ x, float* __restrict__ st){
  __shared__ __align__(16) float xs[22*444];
  const float* xb = x + (size_t)blockIdx.x * (22*438);
  for (int i = threadIdx.x; i < 22*444; i += 256){
    int h = i / 444, w = i - h*444;
    xs[i] = (w < 438) ? xb[h*438 + w] : 0.f;
  }
  __syncthreads();
  for (int t = threadIdx.x; t < 275; t += 256){
    if (t < 22){
      const float4* r = (const float4*)&xs[t*444];
      float4 acc = {0.f,0.f,0.f,0.f};
      for (int w = 0; w < 111; ++w){ float4 v = r[w]; acc.x+=v.x; acc.y+=v.y; acc.z+=v.z; acc.w+=v.w; }
      atomicAdd(&st[ST_SX + t], acc.x+acc.y+acc.z+acc.w);
    } else {
      int rem = t - 22, h = 0;
      while (rem >= 22 - h){ rem -= 22 - h; ++h; }
      int h2 = h + rem;
      const float4* ra = (const float4*)&xs[h*444];
      const float4* rb = (const float4*)&xs[h2*444];
      float4 acc = {0.f,0.f,0.f,0.f};
      for (int w = 0; w < 111; ++w){
        float4 a = ra[w], b = rb[w];
        acc.x = fmaf(a.x,b.x,acc.x); acc.y = fmaf(a.y,b.y,acc.y);
        acc.z = fmaf(a.z,b.z,acc.z); acc.w = fmaf(a.w,b.w,acc.w);
      }
      atomicAdd(&st[ST_SXX + h*22 + h2], acc.x+acc.y+acc.z+acc.w);
    }
  }
}

// ---------------- K1b: fold BN1 into conv1 weights ----------------
__global__ __launch_bounds__(64) void k1b_fold(const float* __restrict__ W1, const float* __restrict__ g1,
                                               const float* __restrict__ be1, float* __restrict__ st){
  int c = threadIdx.x;
  if (c >= 22) return;
  const float invN = 1.f / (2048.f*438.f);
  float mcol[22];
  float mu0 = 0.f;
  for (int h = 0; h < 22; ++h){ mcol[h] = W1[c*22 + h]; mu0 = fmaf(mcol[h], st[ST_SX + h], mu0); }
  mu0 *= invN;
  float qf = 0.f;
  for (int h = 0; h < 22; ++h)
    for (int h2 = h; h2 < 22; ++h2){
      float w = mcol[h]*mcol[h2]*st[ST_SXX + h*22 + h2];
      qf += (h2 == h) ? w : 2.f*w;
    }
  qf *= invN;
  float var = qf - mu0*mu0;
  float a1 = g1[c] * rsqrtf(var + 1e-5f);
  for (int h = 0; h < 22; ++h) st[ST_WF + h*22 + c] = a1 * mcol[h];
  st[ST_BF + c] = be1[c] - a1 * mu0;   // b1 cancels exactly
}

// ---------------- K2: collapse conv1+BN1+conv2 -> effective 12-tap conv on x ----------
// Weff[d][h][t] = sum_c W2[d][c][t] * Wf[h][c]   (5280 floats, layout d*264 + h*12 + t)
// pfx[d][k]    = sum_{t<k} sum_c W2[d][c][t] * bf[c]   (prefix, 13 per d) — gives exact
// boundary bias since conv2 zero-pads z (bf only present for valid z columns).
__global__ __launch_bounds__(256) void k2_weff(const float* __restrict__ W2, const float* __restrict__ st,
                                               float* __restrict__ weff, float* __restrict__ pfx){
  __shared__ float wf[484];
  __shared__ float bf[22];
  for (int i = threadIdx.x; i < 484; i += 256) wf[i] = st[ST_WF + i];
  if (threadIdx.x < 22) bf[threadIdx.x] = st[ST_BF + threadIdx.x];
  __syncthreads();
  for (int i = threadIdx.x; i < 5280; i += 256){
    int d = i / 264, r = i - d*264, h = r / 12, t = r - h*12;
    float a = 0.f;
    for (int c = 0; c < 22; ++c) a = fmaf(W2[d*264 + c*12 + t], wf[h*22 + c], a);
    weff[i] = a;
  }
  if (threadIdx.x < 20){
    int d = threadIdx.x;
    float run = 0.f;
    pfx[d*13 + 0] = 0.f;
    for (int t = 0; t < 12; ++t){
      float a = 0.f;
      for (int c = 0; c < 22; ++c) a = fmaf(W2[d*264 + c*12 + t], bf[c], a);
      run += a;
      pfx[d*13 + t + 1] = run;
    }
  }
}

// ---------------- K3: direct fused conv (x -> y2), wave-per-channel ----------------
// grid (10, 2048): blockIdx.x = wh + 2*dq. Each wave owns one output channel
// d = dq*4 + wave -> the 12 weights per h are WAVE-UNIFORM: s_load into SGPRs,
// FMA takes SGPR operand (no LDS, no VALU for weights). Lanes cover the w-half
// with 5 cols/lane (stride 5 is odd -> conflict-free LDS b32 reads). LDS holds
// only the x half-window: 20.4 KB -> 8 blocks/CU (100% occupancy target).
// Stats: per-wave shuffle reduce -> 2 global atomics per wave.
__global__ __launch_bounds__(256, 8) void k3_conv(const float* __restrict__ x,
    const float* __restrict__ weff, const float* __restrict__ pfx,
    float* __restrict__ st, float* __restrict__ y2){
  __shared__ __align__(16) float xs[22*232];   // 20.4 KB
  int tid = threadIdx.x;
  int wave = tid >> 6, lane = tid & 63;
  int wh = blockIdx.x & 1, dq = blockIdx.x >> 1;   // wh 0..1, dq 0..4
  int n = blockIdx.y;
  int d = dq*4 + wave;                             // 0..19, wave-uniform
  int wbase = wh*220;
  const float* xb = x + (size_t)n*9636;
  for (int i = tid; i < 22*232; i += 256){
    int h = i / 232, lw = i - h*232;
    int gw = wbase - 6 + lw;
    xs[i] = (gw >= 0 && gw < 438) ? xb[h*438 + gw] : 0.f;
  }
  __syncthreads();
  int dsc = __builtin_amdgcn_readfirstlane(d);
  const float* wp = weff + dsc*264;      // wave-uniform -> s_load
  bool act = lane < 44;
  int base = act ? lane*5 : 0;           // clamp inactive lanes (avoid LDS OOB)
  float acc[5] = {0.f,0.f,0.f,0.f,0.f};
  #pragma unroll 1
  for (int h = 0; h < 22; ++h){
    float4 w0 = *(const float4*)(wp + h*12);
    float4 w1 = *(const float4*)(wp + h*12 + 4);
    float4 w2 = *(const float4*)(wp + h*12 + 8);
    float wt[12] = {w0.x,w0.y,w0.z,w0.w, w1.x,w1.y,w1.z,w1.w, w2.x,w2.y,w2.z,w2.w};
    const float* xr = &xs[h*232 + base];
    float xw[16];
    #pragma unroll
    for (int k = 0; k < 16; ++k) xw[k] = xr[k];
    #pragma unroll
    for (int t = 0; t < 12; ++t)
      #pragma unroll
      for (int j = 0; j < 5; ++j)
        acc[j] = fmaf(wt[t], xw[j+t], acc[j]);
  }
  float s = 0.f, q = 0.f;
  if (act){
    const float* prd = pfx + dsc*13;
    float bias12 = prd[12];            // prd[0] == 0
    float* yb = y2 + (size_t)n*8780 + (size_t)d*439;
    #pragma unroll
    for (int j = 0; j < 5; ++j){
      int gw = wbase + base + j;
      if (gw < 439){
        float bias;
        if (gw >= 6 && gw <= 432) bias = bias12;
        else {
          int lo = 6 - gw; if (lo < 0) lo = 0;
          int hi = 444 - gw; if (hi > 12) hi = 12;
          bias = prd[hi] - prd[lo];    // exact zero-pad boundary bias
        }
        float val = acc[j] + bias;
        yb[gw] = val;
        s += val; q = fmaf(val, val, q);
      }
    }
  }
  #pragma unroll
  for (int off = 32; off; off >>= 1){ s += __shfl_down(s, off); q += __shfl_down(q, off); }
  if (lane == 0){
    atomicAdd(&st[ST_Y2S + d], s);
    atomicAdd(&st[ST_Y2Q + d], q);
  }
}

// ---------------- K4: covariance + Q/K/V congruence (patch-split LDS, float4 dots) ------
__global__ __launch_bounds__(256) void k4_cov_qkv(const float* __restrict__ y2, const float* __restrict__ st,
    const float* __restrict__ g2, const float* __restrict__ Wq, const float* __restrict__ Wk,
    const float* __restrict__ Wv, float* __restrict__ qkv){
  __shared__ __align__(16) float ysp[3][20][148];  // patch-split, zero-padded to 148
  __shared__ float a2s[20];
  __shared__ __align__(16) float Bt[3][18][20];    // [wt][i][d] = a2[d]*W[d][i]
  __shared__ __align__(16) float G3[3][400];
  __shared__ __align__(16) float Tmt[3][360];      // [m][jj*20+p]
  __shared__ float musum3[3][20];
  __shared__ float rtr3[3];
  int tid = threadIdx.x, n = blockIdx.x;
  if (tid < 20){
    const float invN = 1.f/(2048.f*439.f);
    float s = st[ST_Y2S + tid]*invN;
    float q = st[ST_Y2Q + tid]*invN;
    a2s[tid] = g2[tid] * rsqrtf(q - s*s + 1e-5f);
  }
  const float* yb = y2 + (size_t)n*8780;
  for (int i = tid; i < 8780; i += 256){
    int d = i/439, w = i - d*439;
    int m = (w >= 293) ? 2 : ((w >= 147) ? 1 : 0);
    int lw = w - ((m == 2) ? 293 : ((m == 1) ? 147 : 0));
    ysp[m][d][lw] = yb[i];
  }
  if (tid < 100){   // zero the pad slots
    int d = tid/5, k = tid - d*5;
    int m = (k == 0) ? 0 : ((k < 3) ? 1 : 2);
    int lw = (k == 0) ? 147 : ((k == 1 || k == 3) ? 146 : 147);
    ysp[m][d][lw] = 0.f;
  }
  __syncthreads();
  for (int i = tid; i < 1140; i += 256){
    if (i < 1080){
      int wt = i/360, r = i - wt*360; int d = r/18, jj = r - d*18;
      const float* Wm = (wt==0) ? Wq : ((wt==1) ? Wk : Wv);
      Bt[wt][jj][d] = a2s[d]*Wm[d*18 + jj];
    } else {
      int t = i - 1080; int m = t/20, d = t - m*20;
      const float4* r = (const float4*)&ysp[m][d][0];
      float4 acc = {0.f,0.f,0.f,0.f};
      #pragma unroll 1
      for (int w = 0; w < 37; ++w){ float4 v = r[w]; acc.x+=v.x; acc.y+=v.y; acc.z+=v.z; acc.w+=v.w; }
      musum3[m][d] = acc.x+acc.y+acc.z+acc.w;
    }
  }
  __syncthreads();
  for (int it = tid; it < 630; it += 256){
    int m = it/210, t = it - m*210;
    int rem = t, c = 0;
    while (rem >= 20 - c){ rem -= 20 - c; ++c; }
    int d = c + rem;
    const float4* ra = (const float4*)&ysp[m][c][0];
    const float4* rb = (const float4*)&ysp[m][d][0];
    float4 acc4 = {0.f,0.f,0.f,0.f};
    #pragma unroll 1
    for (int w = 0; w < 37; ++w){
      float4 a = ra[w], b = rb[w];
      acc4.x = fmaf(a.x,b.x,acc4.x); acc4.y = fmaf(a.y,b.y,acc4.y);
      acc4.z = fmaf(a.z,b.z,acc4.z); acc4.w = fmaf(a.w,b.w,acc4.w);
    }
    float invL = (m == 0) ? (1.f/147.f) : (1.f/146.f);
    float acc = (acc4.x+acc4.y+acc4.z+acc4.w) - musum3[m][c]*musum3[m][d]*invL;
    G3[m][c*20 + d] = acc; G3[m][d*20 + c] = acc;
  }
  __syncthreads();
  for (int wt = 0; wt < 3; ++wt){
    for (int i = tid; i < 1083; i += 256){
      if (i < 1080){
        int m = i/360, r = i - m*360; int p = r/18, jj = r - p*18;
        const float4* gr = (const float4*)&G3[m][p*20];
        const float4* br = (const float4*)&Bt[wt][jj][0];
        float4 a4 = {0.f,0.f,0.f,0.f};
        #pragma unroll
        for (int w = 0; w < 5; ++w){
          float4 a = gr[w], b = br[w];
          a4.x = fmaf(a.x,b.x,a4.x); a4.y = fmaf(a.y,b.y,a4.y);
          a4.z = fmaf(a.z,b.z,a4.z); a4.w = fmaf(a.w,b.w,a4.w);
        }
        Tmt[m][jj*20 + p] = a4.x+a4.y+a4.z+a4.w;
      } else if (wt == 0){
        int m = i - 1080;
        float tr = 0.f;
        for (int c = 0; c < 20; ++c){ float a = a2s[c]; tr = fmaf(a*a, G3[m][c*21], tr); }
        rtr3[m] = 1.f/tr;
      }
    }
    __syncthreads();
    for (int it = tid; it < 513; it += 256){
      int m = it/171, t = it - m*171;
      int rem = t, i = 0;
      while (rem >= 18 - i){ rem -= 18 - i; ++i; }
      int jj = i + rem;
      const float4* br = (const float4*)&Bt[wt][i][0];
      const float4* tr = (const float4*)&Tmt[m][jj*20];
      float4 a4 = {0.f,0.f,0.f,0.f};
      #pragma unroll
      for (int w = 0; w < 5; ++w){
        float4 a = br[w], b = tr[w];
        a4.x = fmaf(a.x,b.x,a4.x); a4.y = fmaf(a.y,b.y,a4.y);
        a4.z = fmaf(a.z,b.z,a4.z); a4.w = fmaf(a.w,b.w,a4.w);
      }
      float acc = (a4.x+a4.y+a4.z+a4.w) * rtr3[m];
      if (i == jj) acc += 1e-5f;
      float* outm = qkv + ((size_t)wt*6144 + (size_t)n*3 + m)*324;
      outm[i*18 + jj] = acc; outm[jj*18 + i] = acc;
    }
    __syncthreads();
  }
}

// ---------------- K5: batched 18x18 one-sided (Hestenes) Jacobi ----------------
// B = A (PSD; mode 1 input pre-shifted by SHIFT*I). Columns orthogonalize;
// b_i -> lam_i*u_i. 19 DS ops/round. (c,s) bitwise-identical on both partner
// lanes. mode 0: dst = U log(S) U^T. mode 1: fused triu-GEMV -> outp.
__global__ __launch_bounds__(256, 4) void k5_oneside(const float* __restrict__ src, float* __restrict__ dst,
    int nmat, int mode, const float* __restrict__ Wl, const float* __restrict__ bl,
    float* __restrict__ outp){
  __shared__ __align__(16) float stage[12][384];
  __shared__ __align__(16) float wls[2052];
  __shared__ float outacc[4][4];
  int tid = threadIdx.x;
  int wave = tid >> 6, lane = tid & 63;
  int g = (lane >= 54) ? 3 : (lane >= 36 ? 2 : (lane >= 18 ? 1 : 0));
  int j = lane - g*18;
  int gb = g*18;
  int slot = wave*3 + ((g < 3) ? g : 0);
  int mat = blockIdx.x*12 + wave*3 + g;
  bool act = (g < 3) && (mat < nmat);

  if (mode == 1){
    for (int i = tid; i < 2052; i += 256) wls[i] = Wl[i];
    if (tid < 16) outacc[tid >> 2][tid & 3] = 0.f;
  }

  float b[18];
  float sh = (mode == 1) ? SHIFT : 0.f;
  if (act){
    const float* s = src + (size_t)mat*324 + j*18;
    #pragma unroll
    for (int i = 0; i < 18; ++i) b[i] = s[i] + ((i == j) ? sh : 0.f);
  } else {
    #pragma unroll
    for (int i = 0; i < 18; ++i) b[i] = (i == j) ? 1.f : 0.f;
  }
  float nrm;
  { float n0 = 0.f, n1 = 0.f;
    #pragma unroll
    for (int k = 0; k < 18; k += 2){ n0 = fmaf(b[k],b[k],n0); n1 = fmaf(b[k+1],b[k+1],n1); }
    nrm = n0 + n1; }

  #pragma unroll 1
  for (int sweep = 0; sweep < NSWEEP; ++sweep){
    #pragma unroll
    for (int r = 0; r < 17; ++r){
      int xx = j - 1 - r; if (xx < 0) xx += 17;
      int v = r + 17 - xx; if (v >= 17) v -= 17;
      int m = (j == 0) ? (1 + r) : ((xx == 0) ? 0 : (1 + v));
      bool isp = (j == 0) ? true : ((xx == 0) ? false : (xx <= 8));
      int plane = (gb + m) & 63;
      float rv[18];
      #pragma unroll
      for (int k = 0; k < 18; ++k) rv[k] = __shfl(b[k], plane);
      float on = __shfl(nrm, plane);
      float g0 = 0.f, g1 = 0.f;
      #pragma unroll
      for (int k = 0; k < 18; k += 2){ g0 = fmaf(b[k], rv[k], g0); g1 = fmaf(b[k+1], rv[k+1], g1); }
      float gam = g0 + g1;                        // bitwise equal on both lanes
      float alpha = isp ? nrm : on;
      float beta  = isp ? on  : nrm;
      float tau = (beta - alpha) * 0.5f * __builtin_amdgcn_rcpf(gam);
      float tt = __builtin_amdgcn_rcpf(fabsf(tau) + sqrtf(fmaf(tau, tau, 1.f)));
      float t = (tau >= 0.f) ? tt : -tt;
      if (!(fabsf(gam) > 1e-36f)) t = 0.f;
      float c = __builtin_amdgcn_rsqf(fmaf(t, t, 1.f));
      float s = t*c;
      nrm = fmaf(isp ? -t : t, gam, nrm);
      float sg = isp ? -s : s;
      #pragma unroll
      for (int k = 0; k < 18; ++k) b[k] = fmaf(c, b[k], sg*rv[k]);
    }
  }
  float n0 = 0.f, n1 = 0.f;
  #pragma unroll
  for (int k = 0; k < 18; k += 2){ n0 = fmaf(b[k],b[k],n0); n1 = fmaf(b[k+1],b[k+1],n1); }
  float nf = fmaxf(n0 + n1, 1e-30f);
  float fv = (mode == 0) ? (0.5f * logf(nf)) : fmaxf(sqrtf(nf) - SHIFT, LOGEPS);
  float wv = fv * __builtin_amdgcn_rcpf(nf);
  float* sp = &stage[slot][0];
  if (act){
    #pragma unroll
    for (int k = 0; k < 18; ++k) sp[k*20 + j] = b[k];
    sp[360 + j] = wv;
  }
  __syncthreads();
  if (act){
    float wr[18];
    #pragma unroll
    for (int i = 0; i < 18; ++i) wr[i] = sp[j*20 + i] * sp[360 + i];
    float frow[18];
    #pragma unroll
    for (int i2 = 0; i2 < 18; ++i2){
      const float* br = &sp[i2*20];
      float a0 = 0.f;
      #pragma unroll
      for (int k = 0; k < 16; k += 4){
        float4 v4 = *(const float4*)&br[k];
        a0 = fmaf(wr[k],   v4.x, a0); a0 = fmaf(wr[k+1], v4.y, a0);
        a0 = fmaf(wr[k+2], v4.z, a0); a0 = fmaf(wr[k+3], v4.w, a0);
      }
      a0 = fmaf(wr[16], br[16], a0);
      a0 = fmaf(wr[17], br[17], a0);
      frow[i2] = a0;
    }
    if (mode == 0){
      float* orow = dst + (size_t)mat*324 + j*18;
      #pragma unroll
      for (int i2 = 0; i2 < 18; ++i2) orow[i2] = frow[i2];
    } else {
      int base = (g*171 + j*(37 - j)/2 - j)*4;
      float o0=0.f, o1=0.f, o2=0.f, o3=0.f;
      #pragma unroll
      for (int jj = 0; jj < 18; ++jj){
        if (jj >= j){
          const float* w4 = &wls[base + jj*4];
          o0 = fmaf(frow[jj], w4[0], o0);
          o1 = fmaf(frow[jj], w4[1], o1);
          o2 = fmaf(frow[jj], w4[2], o2);
          o3 = fmaf(frow[jj], w4[3], o3);
        }
      }
      atomicAdd(&outacc[wave][0], o0);
      atomicAdd(&outacc[wave][1], o1);
      atomicAdd(&outacc[wave][2], o2);
      atomicAdd(&outacc[wave][3], o3);
    }
  }
  if (mode == 1){
    __syncthreads();
    if (tid < 16){
      int bi = tid >> 2, o = tid & 3;
      outp[(blockIdx.x*4 + bi)*4 + o] = outacc[bi][o] + bl[o];
    }
  }
}

// ---------------- K6: energies -> scores -> softmax -> mixed (shuffle-reduced) --------
__global__ __launch_bounds__(128) void k6_attnmix(const float* __restrict__ logs, float* __restrict__ mixed){
  __shared__ float lq[972], lk[972], lv[972];
  __shared__ float ew[2][9];
  __shared__ float P[9];
  int b = blockIdx.x, tid = threadIdx.x;
  const float* q  = logs + (size_t)b*972;
  const float* k_ = logs + 1990656 + (size_t)b*972;
  const float* v_ = logs + 3981312 + (size_t)b*972;
  for (int i = tid; i < 972; i += 128){ lq[i] = q[i]; lk[i] = k_[i]; lv[i] = v_[i]; }
  __syncthreads();
  float e[9] = {0.f,0.f,0.f,0.f,0.f,0.f,0.f,0.f,0.f};
  for (int x = tid; x < 324; x += 128){
    float q0 = lq[x], q1 = lq[324+x], q2 = lq[648+x];
    float k0 = lk[x], k1 = lk[324+x], k2 = lk[648+x];
    float d;
    d = q0-k0; e[0] = fmaf(d,d,e[0]);
    d = q0-k1; e[1] = fmaf(d,d,e[1]);
    d = q0-k2; e[2] = fmaf(d,d,e[2]);
    d = q1-k0; e[3] = fmaf(d,d,e[3]);
    d = q1-k1; e[4] = fmaf(d,d,e[4]);
    d = q1-k2; e[5] = fmaf(d,d,e[5]);
    d = q2-k0; e[6] = fmaf(d,d,e[6]);
    d = q2-k1; e[7] = fmaf(d,d,e[7]);
    d = q2-k2; e[8] = fmaf(d,d,e[8]);
  }
  #pragma unroll
  for (int p = 0; p < 9; ++p)
    for (int off = 32; off; off >>= 1) e[p] += __shfl_down(e[p], off);
  if ((tid & 63) == 0){
    #pragma unroll
    for (int p = 0; p < 9; ++p) ew[tid >> 6][p] = e[p];
  }
  __syncthreads();
  if (tid < 3){
    float en0 = ew[0][tid*3+0] + ew[1][tid*3+0];
    float en1 = ew[0][tid*3+1] + ew[1][tid*3+1];
    float en2 = ew[0][tid*3+2] + ew[1][tid*3+2];
    float s0 = 1.f/(1.f + log1pf(en0));
    float s1 = 1.f/(1.f + log1pf(en1));
    float s2 = 1.f/(1.f + log1pf(en2));
    float mx = fmaxf(s0, fmaxf(s1, s2));
    float e0 = expf(s0-mx), e1 = expf(s1-mx), e2 = expf(s2-mx);
    float inv = 1.f/(e0+e1+e2);
    P[tid*3+0] = e0*inv; P[tid*3+1] = e1*inv; P[tid*3+2] = e2*inv;
  }
  __syncthreads();
  float p00=P[0],p01=P[1],p02=P[2],p10=P[3],p11=P[4],p12=P[5],p20=P[6],p21=P[7],p22=P[8];
  float* mb = mixed + (size_t)b*972;
  for (int x = tid; x < 324; x += 128){
    float v0 = lv[x], v1 = lv[324+x], v2 = lv[648+x];
    mb[x]     = p00*v0 + p01*v1 + p02*v2;
    mb[324+x] = p10*v0 + p11*v1 + p12*v2;
    mb[648+x] = p20*v0 + p21*v1 + p22*v2;
  }
}

// ---------------- launcher ----------------
extern "C" void kernel_launch(void* const* d_in, const int* in_sizes, int n_in,
                              void* d_out, int out_size, void* d_ws, size_t ws_size,
                              hipStream_t stream){
  (void)in_sizes; (void)n_in; (void)out_size; (void)ws_size;
  const float* x   = (const float*)d_in[0];
  const float* W1  = (const float*)d_in[1];
  const float* g1  = (const float*)d_in[3];
  const float* be1 = (const float*)d_in[4];
  const float* W2  = (const float*)d_in[5];
  const float* g2  = (const float*)d_in[7];
  const float* Wq  = (const float*)d_in[9];
  const float* Wk  = (const float*)d_in[10];
  const float* Wv  = (const float*)d_in[11];
  const float* Wl  = (const float*)d_in[12];
  const float* bl  = (const float*)d_in[13];
  float* ws    = (float*)d_ws;
  float* y2    = ws + OFF_Y2;
  float* qkv   = ws + OFF_QKV;
  float* weff  = ws + OFF_QKV;          // overlay: qkv region free until k4
  float* pfx   = ws + OFF_QKV + 5280;
  float* logs  = ws + OFF_Y2;    // overlay: y2 dead after k4
  float* mixed = ws + OFF_QKV;   // overlay: qkv dead after k5#1
  float* st    = ws + OFF_ST;
  float* outp  = (float*)d_out;

  k0_zero    <<<dim3(1),       dim3(256), 0, stream>>>(st);
  k1_xstats  <<<dim3(2048),    dim3(256), 0, stream>>>(x, st);
  k1b_fold   <<<dim3(1),       dim3(64),  0, stream>>>(W1, g1, be1, st);
  k2_weff    <<<dim3(1),       dim3(256), 0, stream>>>(W2, st, weff, pfx);
  k3_conv    <<<dim3(10,2048), dim3(256), 0, stream>>>(x, weff, pfx, st, y2);
  k4_cov_qkv <<<dim3(2048),    dim3(256), 0, stream>>>(y2, st, g2, Wq, Wk, Wv, qkv);
  k5_oneside <<<dim3(1536),    dim3(256), 0, stream>>>(qkv, logs, 18432, 0, nullptr, nullptr, nullptr);
  k6_attnmix <<<dim3(2048),    dim3(128), 0, stream>>>(logs, mixed);
  k5_oneside <<<dim3(512),     dim3(256), 0, stream>>>(mixed, nullptr, 6144, 1, Wl, bl, outp);
}

// Round 3
// 776.147 us; speedup vs baseline: 1.8399x; 1.8399x over previous
//
#include <hip/hip_runtime.h>
#include <math.h>

// ---------------- workspace layout (floats) ----------------
#define OFF_Y2   0
#define OFF_QKV  17981440
#define OFF_ST   (17981440 + 5971968)
// stats offsets
#define ST_SX   0
#define ST_SXX  22
#define ST_WF   506
#define ST_BF   990
#define ST_Y2S  1012
#define ST_Y2Q  1032
#define ST_TOT  1052

#define LOGEPS -9.210340371976182f
#define NSWEEP 5   // 4 sweeps FAILED: absmax 2.29e-2 > 1.91e-2 thr (r7). 5 -> 3.9e-3.
#define SHIFT  12.0f   // mixed eigenvalues in [-11.62, ~1e-4] -> shifted PSD

// ---------------- K0: zero stats ----------------
__global__ __launch_bounds__(256) void k0_zero(float* __restrict__ st){
  for (int i = threadIdx.x; i < ST_TOT; i += 256) st[i] = 0.f;
}

// ---------------- K1: x second moments (for closed-form BN1 stats) ----------------
__global__ __launch_bounds__(256) void k1_xstats(const float* __restrict__ x, float* __restrict__ st){
  __shared__ __align__(16) float xs[22*444];
  const float* xb = x + (size_t)blockIdx.x * (22*438);
  for (int i = threadIdx.x; i < 22*444; i += 256){
    int h = i / 444, w = i - h*444;
    xs[i] = (w < 438) ? xb[h*438 + w] : 0.f;
  }
  __syncthreads();
  for (int t = threadIdx.x; t < 275; t += 256){
    if (t < 22){
      const float4* r = (const float4*)&xs[t*444];
      float4 acc = {0.f,0.f,0.f,0.f};
      for (int w = 0; w < 111; ++w){ float4 v = r[w]; acc.x+=v.x; acc.y+=v.y; acc.z+=v.z; acc.w+=v.w; }
      atomicAdd(&st[ST_SX + t], acc.x+acc.y+acc.z+acc.w);
    } else {
      int rem = t - 22, h = 0;
      while (rem >= 22 - h){ rem -= 22 - h; ++h; }
      int h2 = h + rem;
      const float4* ra = (const float4*)&xs[h*444];
      const float4* rb = (const float4*)&xs[h2*444];
      float4 acc = {0.f,0.f,0.f,0.f};
      for (int w = 0; w < 111; ++w){
        float4 a = ra[w], b = rb[w];
        acc.x = fmaf(a.x,b.x,acc.x); acc.y = fmaf(a.y,b.y,acc.y);
        acc.z = fmaf(a.z,b.z,acc.z); acc.w = fmaf(a.w,b.w,acc.w);
      }
      atomicAdd(&st[ST_SXX + h*22 + h2], acc.x+acc.y+acc.z+acc.w);
    }
  }
}

// ---------------- K1b: fold BN1 into conv1 weights ----------------
__global__ __launch_bounds__(64) void k1b_fold(const float* __restrict__ W1, const float* __restrict__ g1,
                                               const float* __restrict__ be1, float* __restrict__ st){
  int c = threadIdx.x;
  if (c >= 22) return;
  const float invN = 1.f / (2048.f*438.f);
  float mcol[22];
  float mu0 = 0.f;
  for (int h = 0; h < 22; ++h){ mcol[h] = W1[c*22 + h]; mu0 = fmaf(mcol[h], st[ST_SX + h], mu0); }
  mu0 *= invN;
  float qf = 0.f;
  for (int h = 0; h < 22; ++h)
    for (int h2 = h; h2 < 22; ++h2){
      float w = mcol[h]*mcol[h2]*st[ST_SXX + h*22 + h2];
      qf += (h2 == h) ? w : 2.f*w;
    }
  qf *= invN;
  float var = qf - mu0*mu0;
  float a1 = g1[c] * rsqrtf(var + 1e-5f);
  for (int h = 0; h < 22; ++h) st[ST_WF + h*22 + c] = a1 * mcol[h];
  st[ST_BF + c] = be1[c] - a1 * mu0;   // b1 cancels exactly
}

// ---------------- K2: collapse conv1+BN1+conv2 -> effective 12-tap conv on x ----------
// Weff[d][h][t] = sum_c W2[d][c][t] * Wf[h][c]   (5280 floats, layout d*264 + h*12 + t)
// pfx[d][k]    = sum_{t<k} sum_c W2[d][c][t] * bf[c]   (prefix, 13 per d) — gives exact
// boundary bias since conv2 zero-pads z (bf only present for valid z columns).
__global__ __launch_bounds__(256) void k2_weff(const float* __restrict__ W2, const float* __restrict__ st,
                                               float* __restrict__ weff, float* __restrict__ pfx){
  __shared__ float wf[484];
  __shared__ float bf[22];
  for (int i = threadIdx.x; i < 484; i += 256) wf[i] = st[ST_WF + i];
  if (threadIdx.x < 22) bf[threadIdx.x] = st[ST_BF + threadIdx.x];
  __syncthreads();
  for (int i = threadIdx.x; i < 5280; i += 256){
    int d = i / 264, r = i - d*264, h = r / 12, t = r - h*12;
    float a = 0.f;
    for (int c = 0; c < 22; ++c) a = fmaf(W2[d*264 + c*12 + t], wf[h*22 + c], a);
    weff[i] = a;
  }
  if (threadIdx.x < 20){
    int d = threadIdx.x;
    float run = 0.f;
    pfx[d*13 + 0] = 0.f;
    for (int t = 0; t < 12; ++t){
      float a = 0.f;
      for (int c = 0; c < 22; ++c) a = fmaf(W2[d*264 + c*12 + t], bf[c], a);
      run += a;
      pfx[d*13 + t + 1] = run;
    }
  }
}

// ---------------- K3: direct fused conv (x -> y2), column-per-thread, all-d ----------
// grid (2048): one block per sample. 512 threads, thread = output column gw,
// acc[20] (all channels). Weights read at WAVE-UNIFORM global addresses ->
// s_load into SGPRs (zero VGPR/LDS cost, broadcast via scalar cache). LDS
// holds only the padded x window (41 KB -> 3 blocks/CU = 24 waves = 75%).
// Per h: 12 LDS b32 reads feed 240 FMAs (20:1). x staged ONCE per sample.
// NOTE r2 lesson: keep >=20 live accumulators per lane; per-lane LDS windows
// with <128 FMA/h made the compiler drop to 20 VGPRs + LDS re-reads (877us).
__global__ __launch_bounds__(512, 6) void k3_conv(const float* __restrict__ x,
    const float* __restrict__ weff, const float* __restrict__ pfx,
    float* __restrict__ st, float* __restrict__ y2){
  __shared__ __align__(16) float xs[22*452];   // 39.8 KB, row stride 452 (16B-aligned)
  __shared__ float ps[260];
  __shared__ float sloc[20], qloc[20];
  int tid = threadIdx.x;
  int n = blockIdx.x;
  const float* xb = x + (size_t)n*9636;
  for (int i = tid; i < 22*452; i += 512){
    int h = i / 452, w = i - h*452;
    int gx = w - 6;
    xs[i] = (gx >= 0 && gx < 438) ? xb[h*438 + gx] : 0.f;
  }
  if (tid < 260) ps[tid] = pfx[tid];
  if (tid < 40){ if (tid < 20) sloc[tid] = 0.f; else qloc[tid-20] = 0.f; }
  __syncthreads();
  bool act = tid < 439;
  int gw = act ? tid : 0;            // clamp inactive lanes (no LDS OOB)
  float acc[20];
  #pragma unroll
  for (int d = 0; d < 20; ++d) acc[d] = 0.f;
  #pragma unroll 1
  for (int h = 0; h < 22; ++h){
    const float* xr = &xs[h*452 + gw];
    float xw[12];
    #pragma unroll
    for (int t = 0; t < 12; ++t) xw[t] = xr[t];
    const float* wp = weff + h*12;   // wave-uniform -> s_load
    #pragma unroll
    for (int d = 0; d < 20; ++d){
      const float* wr = wp + d*264;
      #pragma unroll
      for (int t = 0; t < 12; ++t)
        acc[d] = fmaf(wr[t], xw[t], acc[d]);
    }
  }
  int lo = 6 - gw; if (lo < 0) lo = 0;
  int hi = 444 - gw; if (hi > 12) hi = 12;
  float* yb = y2 + (size_t)n*8780 + gw;
  #pragma unroll
  for (int d = 0; d < 20; ++d){
    float val = acc[d] + (ps[d*13 + hi] - ps[d*13 + lo]);  // exact zero-pad bias
    float sv = act ? val : 0.f;
    float qv = act ? val*val : 0.f;
    if (act) yb[(size_t)d*439] = val;
    #pragma unroll
    for (int off = 32; off; off >>= 1){ sv += __shfl_down(sv, off); qv += __shfl_down(qv, off); }
    if ((tid & 63) == 0){ atomicAdd(&sloc[d], sv); atomicAdd(&qloc[d], qv); }
  }
  __syncthreads();
  if (tid < 20){
    atomicAdd(&st[ST_Y2S + tid], sloc[tid]);
    atomicAdd(&st[ST_Y2Q + tid], qloc[tid]);
  }
}

// ---------------- K4: covariance + Q/K/V congruence (patch-split LDS, float4 dots) ------
__global__ __launch_bounds__(256) void k4_cov_qkv(const float* __restrict__ y2, const float* __restrict__ st,
    const float* __restrict__ g2, const float* __restrict__ Wq, const float* __restrict__ Wk,
    const float* __restrict__ Wv, float* __restrict__ qkv){
  __shared__ __align__(16) float ysp[3][20][148];  // patch-split, zero-padded to 148
  __shared__ float a2s[20];
  __shared__ __align__(16) float Bt[3][18][20];    // [wt][i][d] = a2[d]*W[d][i]
  __shared__ __align__(16) float G3[3][400];
  __shared__ __align__(16) float Tmt[3][360];      // [m][jj*20+p]
  __shared__ float musum3[3][20];
  __shared__ float rtr3[3];
  int tid = threadIdx.x, n = blockIdx.x;
  if (tid < 20){
    const float invN = 1.f/(2048.f*439.f);
    float s = st[ST_Y2S + tid]*invN;
    float q = st[ST_Y2Q + tid]*invN;
    a2s[tid] = g2[tid] * rsqrtf(q - s*s + 1e-5f);
  }
  const float* yb = y2 + (size_t)n*8780;
  for (int i = tid; i < 8780; i += 256){
    int d = i/439, w = i - d*439;
    int m = (w >= 293) ? 2 : ((w >= 147) ? 1 : 0);
    int lw = w - ((m == 2) ? 293 : ((m == 1) ? 147 : 0));
    ysp[m][d][lw] = yb[i];
  }
  if (tid < 100){   // zero the pad slots
    int d = tid/5, k = tid - d*5;
    int m = (k == 0) ? 0 : ((k < 3) ? 1 : 2);
    int lw = (k == 0) ? 147 : ((k == 1 || k == 3) ? 146 : 147);
    ysp[m][d][lw] = 0.f;
  }
  __syncthreads();
  for (int i = tid; i < 1140; i += 256){
    if (i < 1080){
      int wt = i/360, r = i - wt*360; int d = r/18, jj = r - d*18;
      const float* Wm = (wt==0) ? Wq : ((wt==1) ? Wk : Wv);
      Bt[wt][jj][d] = a2s[d]*Wm[d*18 + jj];
    } else {
      int t = i - 1080; int m = t/20, d = t - m*20;
      const float4* r = (const float4*)&ysp[m][d][0];
      float4 acc = {0.f,0.f,0.f,0.f};
      #pragma unroll 1
      for (int w = 0; w < 37; ++w){ float4 v = r[w]; acc.x+=v.x; acc.y+=v.y; acc.z+=v.z; acc.w+=v.w; }
      musum3[m][d] = acc.x+acc.y+acc.z+acc.w;
    }
  }
  __syncthreads();
  for (int it = tid; it < 630; it += 256){
    int m = it/210, t = it - m*210;
    int rem = t, c = 0;
    while (rem >= 20 - c){ rem -= 20 - c; ++c; }
    int d = c + rem;
    const float4* ra = (const float4*)&ysp[m][c][0];
    const float4* rb = (const float4*)&ysp[m][d][0];
    float4 acc4 = {0.f,0.f,0.f,0.f};
    #pragma unroll 1
    for (int w = 0; w < 37; ++w){
      float4 a = ra[w], b = rb[w];
      acc4.x = fmaf(a.x,b.x,acc4.x); acc4.y = fmaf(a.y,b.y,acc4.y);
      acc4.z = fmaf(a.z,b.z,acc4.z); acc4.w = fmaf(a.w,b.w,acc4.w);
    }
    float invL = (m == 0) ? (1.f/147.f) : (1.f/146.f);
    float acc = (acc4.x+acc4.y+acc4.z+acc4.w) - musum3[m][c]*musum3[m][d]*invL;
    G3[m][c*20 + d] = acc; G3[m][d*20 + c] = acc;
  }
  __syncthreads();
  for (int wt = 0; wt < 3; ++wt){
    for (int i = tid; i < 1083; i += 256){
      if (i < 1080){
        int m = i/360, r = i - m*360; int p = r/18, jj = r - p*18;
        const float4* gr = (const float4*)&G3[m][p*20];
        const float4* br = (const float4*)&Bt[wt][jj][0];
        float4 a4 = {0.f,0.f,0.f,0.f};
        #pragma unroll
        for (int w = 0; w < 5; ++w){
          float4 a = gr[w], b = br[w];
          a4.x = fmaf(a.x,b.x,a4.x); a4.y = fmaf(a.y,b.y,a4.y);
          a4.z = fmaf(a.z,b.z,a4.z); a4.w = fmaf(a.w,b.w,a4.w);
        }
        Tmt[m][jj*20 + p] = a4.x+a4.y+a4.z+a4.w;
      } else if (wt == 0){
        int m = i - 1080;
        float tr = 0.f;
        for (int c = 0; c < 20; ++c){ float a = a2s[c]; tr = fmaf(a*a, G3[m][c*21], tr); }
        rtr3[m] = 1.f/tr;
      }
    }
    __syncthreads();
    for (int it = tid; it < 513; it += 256){
      int m = it/171, t = it - m*171;
      int rem = t, i = 0;
      while (rem >= 18 - i){ rem -= 18 - i; ++i; }
      int jj = i + rem;
      const float4* br = (const float4*)&Bt[wt][i][0];
      const float4* tr = (const float4*)&Tmt[m][jj*20];
      float4 a4 = {0.f,0.f,0.f,0.f};
      #pragma unroll
      for (int w = 0; w < 5; ++w){
        float4 a = br[w], b = tr[w];
        a4.x = fmaf(a.x,b.x,a4.x); a4.y = fmaf(a.y,b.y,a4.y);
        a4.z = fmaf(a.z,b.z,a4.z); a4.w = fmaf(a.w,b.w,a4.w);
      }
      float acc = (a4.x+a4.y+a4.z+a4.w) * rtr3[m];
      if (i == jj) acc += 1e-5f;
      float* outm = qkv + ((size_t)wt*6144 + (size_t)n*3 + m)*324;
      outm[i*18 + jj] = acc; outm[jj*18 + i] = acc;
    }
    __syncthreads();
  }
}

// ---------------- K5: batched 18x18 one-sided (Hestenes) Jacobi ----------------
// B = A (PSD; mode 1 input pre-shifted by SHIFT*I). Columns orthogonalize;
// b_i -> lam_i*u_i. 19 DS ops/round. (c,s) bitwise-identical on both partner
// lanes. mode 0: dst = U log(S) U^T. mode 1: fused triu-GEMV -> outp.
__global__ __launch_bounds__(256, 4) void k5_oneside(const float* __restrict__ src, float* __restrict__ dst,
    int nmat, int mode, const float* __restrict__ Wl, const float* __restrict__ bl,
    float* __restrict__ outp){
  __shared__ __align__(16) float stage[12][384];
  __shared__ __align__(16) float wls[2052];
  __shared__ float outacc[4][4];
  int tid = threadIdx.x;
  int wave = tid >> 6, lane = tid & 63;
  int g = (lane >= 54) ? 3 : (lane >= 36 ? 2 : (lane >= 18 ? 1 : 0));
  int j = lane - g*18;
  int gb = g*18;
  int slot = wave*3 + ((g < 3) ? g : 0);
  int mat = blockIdx.x*12 + wave*3 + g;
  bool act = (g < 3) && (mat < nmat);

  if (mode == 1){
    for (int i = tid; i < 2052; i += 256) wls[i] = Wl[i];
    if (tid < 16) outacc[tid >> 2][tid & 3] = 0.f;
  }

  float b[18];
  float sh = (mode == 1) ? SHIFT : 0.f;
  if (act){
    const float* s = src + (size_t)mat*324 + j*18;
    #pragma unroll
    for (int i = 0; i < 18; ++i) b[i] = s[i] + ((i == j) ? sh : 0.f);
  } else {
    #pragma unroll
    for (int i = 0; i < 18; ++i) b[i] = (i == j) ? 1.f : 0.f;
  }
  float nrm;
  { float n0 = 0.f, n1 = 0.f;
    #pragma unroll
    for (int k = 0; k < 18; k += 2){ n0 = fmaf(b[k],b[k],n0); n1 = fmaf(b[k+1],b[k+1],n1); }
    nrm = n0 + n1; }

  #pragma unroll 1
  for (int sweep = 0; sweep < NSWEEP; ++sweep){
    #pragma unroll
    for (int r = 0; r < 17; ++r){
      int xx = j - 1 - r; if (xx < 0) xx += 17;
      int v = r + 17 - xx; if (v >= 17) v -= 17;
      int m = (j == 0) ? (1 + r) : ((xx == 0) ? 0 : (1 + v));
      bool isp = (j == 0) ? true : ((xx == 0) ? false : (xx <= 8));
      int plane = (gb + m) & 63;
      float rv[18];
      #pragma unroll
      for (int k = 0; k < 18; ++k) rv[k] = __shfl(b[k], plane);
      float on = __shfl(nrm, plane);
      float g0 = 0.f, g1 = 0.f;
      #pragma unroll
      for (int k = 0; k < 18; k += 2){ g0 = fmaf(b[k], rv[k], g0); g1 = fmaf(b[k+1], rv[k+1], g1); }
      float gam = g0 + g1;                        // bitwise equal on both lanes
      float alpha = isp ? nrm : on;
      float beta  = isp ? on  : nrm;
      float tau = (beta - alpha) * 0.5f * __builtin_amdgcn_rcpf(gam);
      float tt = __builtin_amdgcn_rcpf(fabsf(tau) + sqrtf(fmaf(tau, tau, 1.f)));
      float t = (tau >= 0.f) ? tt : -tt;
      if (!(fabsf(gam) > 1e-36f)) t = 0.f;
      float c = __builtin_amdgcn_rsqf(fmaf(t, t, 1.f));
      float s = t*c;
      nrm = fmaf(isp ? -t : t, gam, nrm);
      float sg = isp ? -s : s;
      #pragma unroll
      for (int k = 0; k < 18; ++k) b[k] = fmaf(c, b[k], sg*rv[k]);
    }
  }
  float n0 = 0.f, n1 = 0.f;
  #pragma unroll
  for (int k = 0; k < 18; k += 2){ n0 = fmaf(b[k],b[k],n0); n1 = fmaf(b[k+1],b[k+1],n1); }
  float nf = fmaxf(n0 + n1, 1e-30f);
  float fv = (mode == 0) ? (0.5f * logf(nf)) : fmaxf(sqrtf(nf) - SHIFT, LOGEPS);
  float wv = fv * __builtin_amdgcn_rcpf(nf);
  float* sp = &stage[slot][0];
  if (act){
    #pragma unroll
    for (int k = 0; k < 18; ++k) sp[k*20 + j] = b[k];
    sp[360 + j] = wv;
  }
  __syncthreads();
  if (act){
    float wr[18];
    #pragma unroll
    for (int i = 0; i < 18; ++i) wr[i] = sp[j*20 + i] * sp[360 + i];
    float frow[18];
    #pragma unroll
    for (int i2 = 0; i2 < 18; ++i2){
      const float* br = &sp[i2*20];
      float a0 = 0.f;
      #pragma unroll
      for (int k = 0; k < 16; k += 4){
        float4 v4 = *(const float4*)&br[k];
        a0 = fmaf(wr[k],   v4.x, a0); a0 = fmaf(wr[k+1], v4.y, a0);
        a0 = fmaf(wr[k+2], v4.z, a0); a0 = fmaf(wr[k+3], v4.w, a0);
      }
      a0 = fmaf(wr[16], br[16], a0);
      a0 = fmaf(wr[17], br[17], a0);
      frow[i2] = a0;
    }
    if (mode == 0){
      float* orow = dst + (size_t)mat*324 + j*18;
      #pragma unroll
      for (int i2 = 0; i2 < 18; ++i2) orow[i2] = frow[i2];
    } else {
      int base = (g*171 + j*(37 - j)/2 - j)*4;
      float o0=0.f, o1=0.f, o2=0.f, o3=0.f;
      #pragma unroll
      for (int jj = 0; jj < 18; ++jj){
        if (jj >= j){
          const float* w4 = &wls[base + jj*4];
          o0 = fmaf(frow[jj], w4[0], o0);
          o1 = fmaf(frow[jj], w4[1], o1);
          o2 = fmaf(frow[jj], w4[2], o2);
          o3 = fmaf(frow[jj], w4[3], o3);
        }
      }
      atomicAdd(&outacc[wave][0], o0);
      atomicAdd(&outacc[wave][1], o1);
      atomicAdd(&outacc[wave][2], o2);
      atomicAdd(&outacc[wave][3], o3);
    }
  }
  if (mode == 1){
    __syncthreads();
    if (tid < 16){
      int bi = tid >> 2, o = tid & 3;
      outp[(blockIdx.x*4 + bi)*4 + o] = outacc[bi][o] + bl[o];
    }
  }
}

// ---------------- K6: energies -> scores -> softmax -> mixed (shuffle-reduced) --------
__global__ __launch_bounds__(128) void k6_attnmix(const float* __restrict__ logs, float* __restrict__ mixed){
  __shared__ float lq[972], lk[972], lv[972];
  __shared__ float ew[2][9];
  __shared__ float P[9];
  int b = blockIdx.x, tid = threadIdx.x;
  const float* q  = logs + (size_t)b*972;
  const float* k_ = logs + 1990656 + (size_t)b*972;
  const float* v_ = logs + 3981312 + (size_t)b*972;
  for (int i = tid; i < 972; i += 128){ lq[i] = q[i]; lk[i] = k_[i]; lv[i] = v_[i]; }
  __syncthreads();
  float e[9] = {0.f,0.f,0.f,0.f,0.f,0.f,0.f,0.f,0.f};
  for (int x = tid; x < 324; x += 128){
    float q0 = lq[x], q1 = lq[324+x], q2 = lq[648+x];
    float k0 = lk[x], k1 = lk[324+x], k2 = lk[648+x];
    float d;
    d = q0-k0; e[0] = fmaf(d,d,e[0]);
    d = q0-k1; e[1] = fmaf(d,d,e[1]);
    d = q0-k2; e[2] = fmaf(d,d,e[2]);
    d = q1-k0; e[3] = fmaf(d,d,e[3]);
    d = q1-k1; e[4] = fmaf(d,d,e[4]);
    d = q1-k2; e[5] = fmaf(d,d,e[5]);
    d = q2-k0; e[6] = fmaf(d,d,e[6]);
    d = q2-k1; e[7] = fmaf(d,d,e[7]);
    d = q2-k2; e[8] = fmaf(d,d,e[8]);
  }
  #pragma unroll
  for (int p = 0; p < 9; ++p)
    for (int off = 32; off; off >>= 1) e[p] += __shfl_down(e[p], off);
  if ((tid & 63) == 0){
    #pragma unroll
    for (int p = 0; p < 9; ++p) ew[tid >> 6][p] = e[p];
  }
  __syncthreads();
  if (tid < 3){
    float en0 = ew[0][tid*3+0] + ew[1][tid*3+0];
    float en1 = ew[0][tid*3+1] + ew[1][tid*3+1];
    float en2 = ew[0][tid*3+2] + ew[1][tid*3+2];
    float s0 = 1.f/(1.f + log1pf(en0));
    float s1 = 1.f/(1.f + log1pf(en1));
    float s2 = 1.f/(1.f + log1pf(en2));
    float mx = fmaxf(s0, fmaxf(s1, s2));
    float e0 = expf(s0-mx), e1 = expf(s1-mx), e2 = expf(s2-mx);
    float inv = 1.f/(e0+e1+e2);
    P[tid*3+0] = e0*inv; P[tid*3+1] = e1*inv; P[tid*3+2] = e2*inv;
  }
  __syncthreads();
  float p00=P[0],p01=P[1],p02=P[2],p10=P[3],p11=P[4],p12=P[5],p20=P[6],p21=P[7],p22=P[8];
  float* mb = mixed + (size_t)b*972;
  for (int x = tid; x < 324; x += 128){
    float v0 = lv[x], v1 = lv[324+x], v2 = lv[648+x];
    mb[x]     = p00*v0 + p01*v1 + p02*v2;
    mb[324+x] = p10*v0 + p11*v1 + p12*v2;
    mb[648+x] = p20*v0 + p21*v1 + p22*v2;
  }
}

// ---------------- launcher ----------------
extern "C" void kernel_launch(void* const* d_in, const int* in_sizes, int n_in,
                              void* d_out, int out_size, void* d_ws, size_t ws_size,
                              hipStream_t stream){
  (void)in_sizes; (void)n_in; (void)out_size; (void)ws_size;
  const float* x   = (const float*)d_in[0];
  const float* W1  = (const float*)d_in[1];
  const float* g1  = (const float*)d_in[3];
  const float* be1 = (const float*)d_in[4];
  const float* W2  = (const float*)d_in[5];
  const float* g2  = (const float*)d_in[7];
  const float* Wq  = (const float*)d_in[9];
  const float* Wk  = (const float*)d_in[10];
  const float* Wv  = (const float*)d_in[11];
  const float* Wl  = (const float*)d_in[12];
  const float* bl  = (const float*)d_in[13];
  float* ws    = (float*)d_ws;
  float* y2    = ws + OFF_Y2;
  float* qkv   = ws + OFF_QKV;
  float* weff  = ws + OFF_QKV;          // overlay: qkv region free until k4
  float* pfx   = ws + OFF_QKV + 5280;
  float* logs  = ws + OFF_Y2;    // overlay: y2 dead after k4
  float* mixed = ws + OFF_QKV;   // overlay: qkv dead after k5#1
  float* st    = ws + OFF_ST;
  float* outp  = (float*)d_out;

  k0_zero    <<<dim3(1),       dim3(256), 0, stream>>>(st);
  k1_xstats  <<<dim3(2048),    dim3(256), 0, stream>>>(x, st);
  k1b_fold   <<<dim3(1),       dim3(64),  0, stream>>>(W1, g1, be1, st);
  k2_weff    <<<dim3(1),       dim3(256), 0, stream>>>(W2, st, weff, pfx);
  k3_conv    <<<dim3(2048),    dim3(512), 0, stream>>>(x, weff, pfx, st, y2);
  k4_cov_qkv <<<dim3(2048),    dim3(256), 0, stream>>>(y2, st, g2, Wq, Wk, Wv, qkv);
  k5_oneside <<<dim3(1536),    dim3(256), 0, stream>>>(qkv, logs, 18432, 0, nullptr, nullptr, nullptr);
  k6_attnmix <<<dim3(2048),    dim3(128), 0, stream>>>(logs, mixed);
  k5_oneside <<<dim3(512),     dim3(256), 0, stream>>>(mixed, nullptr, 6144, 1, Wl, bl, outp);
}

// Round 4
// 659.379 us; speedup vs baseline: 2.1658x; 1.1771x over previous
//
#include <hip/hip_runtime.h>
#include <math.h>

// ---------------- workspace layout (floats) ----------------
#define OFF_Y2   0
#define OFF_QKV  17981440
#define OFF_ST   (17981440 + 5971968)
// stats offsets
#define ST_SX   0
#define ST_SXX  22
#define ST_WF   506
#define ST_BF   990
#define ST_Y2S  1012
#define ST_Y2Q  1032
#define ST_TOT  1052

#define LOGEPS -9.210340371976182f
#define NSWEEP 5   // 4 sweeps FAILED: absmax 2.29e-2 > 1.91e-2 thr (r7). 5 -> 3.9e-3.
#define SHIFT  12.0f   // mixed eigenvalues in [-11.62, ~1e-4] -> shifted PSD

// ---------------- K0: zero stats ----------------
__global__ __launch_bounds__(256) void k0_zero(float* __restrict__ st){
  for (int i = threadIdx.x; i < ST_TOT; i += 256) st[i] = 0.f;
}

// ---------------- K1: x second moments (for closed-form BN1 stats) ----------------
__global__ __launch_bounds__(256) void k1_xstats(const float* __restrict__ x, float* __restrict__ st){
  __shared__ __align__(16) float xs[22*444];
  const float* xb = x + (size_t)blockIdx.x * (22*438);
  for (int i = threadIdx.x; i < 22*444; i += 256){
    int h = i / 444, w = i - h*444;
    xs[i] = (w < 438) ? xb[h*438 + w] : 0.f;
  }
  __syncthreads();
  for (int t = threadIdx.x; t < 275; t += 256){
    if (t < 22){
      const float4* r = (const float4*)&xs[t*444];
      float4 acc = {0.f,0.f,0.f,0.f};
      for (int w = 0; w < 111; ++w){ float4 v = r[w]; acc.x+=v.x; acc.y+=v.y; acc.z+=v.z; acc.w+=v.w; }
      atomicAdd(&st[ST_SX + t], acc.x+acc.y+acc.z+acc.w);
    } else {
      int rem = t - 22, h = 0;
      while (rem >= 22 - h){ rem -= 22 - h; ++h; }
      int h2 = h + rem;
      const float4* ra = (const float4*)&xs[h*444];
      const float4* rb = (const float4*)&xs[h2*444];
      float4 acc = {0.f,0.f,0.f,0.f};
      for (int w = 0; w < 111; ++w){
        float4 a = ra[w], b = rb[w];
        acc.x = fmaf(a.x,b.x,acc.x); acc.y = fmaf(a.y,b.y,acc.y);
        acc.z = fmaf(a.z,b.z,acc.z); acc.w = fmaf(a.w,b.w,acc.w);
      }
      atomicAdd(&st[ST_SXX + h*22 + h2], acc.x+acc.y+acc.z+acc.w);
    }
  }
}

// ---------------- K1b: fold BN1 into conv1 weights ----------------
__global__ __launch_bounds__(64) void k1b_fold(const float* __restrict__ W1, const float* __restrict__ g1,
                                               const float* __restrict__ be1, float* __restrict__ st){
  int c = threadIdx.x;
  if (c >= 22) return;
  const float invN = 1.f / (2048.f*438.f);
  float mcol[22];
  float mu0 = 0.f;
  for (int h = 0; h < 22; ++h){ mcol[h] = W1[c*22 + h]; mu0 = fmaf(mcol[h], st[ST_SX + h], mu0); }
  mu0 *= invN;
  float qf = 0.f;
  for (int h = 0; h < 22; ++h)
    for (int h2 = h; h2 < 22; ++h2){
      float w = mcol[h]*mcol[h2]*st[ST_SXX + h*22 + h2];
      qf += (h2 == h) ? w : 2.f*w;
    }
  qf *= invN;
  float var = qf - mu0*mu0;
  float a1 = g1[c] * rsqrtf(var + 1e-5f);
  for (int h = 0; h < 22; ++h) st[ST_WF + h*22 + c] = a1 * mcol[h];
  st[ST_BF + c] = be1[c] - a1 * mu0;   // b1 cancels exactly
}

// ---------------- K2: collapse conv1+BN1+conv2 -> effective 12-tap conv on x ----------
// weff2[dg][h][dl][t] = sum_c W2[(dg*5+dl)*264 + c*12 + t] * Wf[h][c]
//   (5280 floats; 60 CONTIGUOUS floats per (dg,h) -> k3's per-h scalar batch is
//    15 consecutive dwordx4 -> wide s_load, ONE lgkm wait per h. r3 lesson:
//    240 floats/h blew the SGPR budget -> 4 serialized batches -> 45% VALUBusy.)
// pfx[d][k] = sum_{t<k} sum_c W2[d][c][t] * bf[c]  (exact zero-pad boundary bias)
__global__ __launch_bounds__(256) void k2_weff(const float* __restrict__ W2, const float* __restrict__ st,
                                               float* __restrict__ weff2, float* __restrict__ pfx){
  __shared__ float wf[484];
  __shared__ float bf[22];
  for (int i = threadIdx.x; i < 484; i += 256) wf[i] = st[ST_WF + i];
  if (threadIdx.x < 22) bf[threadIdx.x] = st[ST_BF + threadIdx.x];
  __syncthreads();
  for (int i = threadIdx.x; i < 5280; i += 256){
    int t = i % 12; int tmp = i / 12;
    int dl = tmp % 5; tmp /= 5;
    int h = tmp % 22; int dg = tmp / 22;
    int d = dg*5 + dl;
    float a = 0.f;
    for (int c = 0; c < 22; ++c) a = fmaf(W2[d*264 + c*12 + t], wf[h*22 + c], a);
    weff2[i] = a;
  }
  if (threadIdx.x < 20){
    int d = threadIdx.x;
    float run = 0.f;
    pfx[d*13 + 0] = 0.f;
    for (int t = 0; t < 12; ++t){
      float a = 0.f;
      for (int c = 0; c < 22; ++c) a = fmaf(W2[d*264 + c*12 + t], bf[c], a);
      run += a;
      pfx[d*13 + t + 1] = run;
    }
  }
}

// ---------------- K3: direct fused conv (x -> y2), 5d x 4col per thread ----------
// grid (2048): one block per sample, 512 threads. Wave-pair owns 5 channels
// (dg = wave>>1, wave-uniform via readfirstlane); thread owns 4 consecutive
// output columns. Per h: 15 s_load_dwordx4 (60 weight floats, ONE SGPR batch,
// one lgkm wait) + 4 ds_read_b128 (x window, conflict-free) + 240 FMAs.
// acc[5][4]+xw[16] ~ 45 VGPR (proven-good regime, r2 lesson: keep >=20 live
// accs). LDS 41 KB -> 3 blocks/CU = 24 waves (75%). x staged ONCE per sample.
__global__ __launch_bounds__(512, 3) void k3_conv(const float* __restrict__ x,
    const float* __restrict__ weff2, const float* __restrict__ pfx,
    float* __restrict__ st, float* __restrict__ y2){
  __shared__ __align__(16) float xs[22*452];   // 39.8 KB, row stride 452 (16B-aligned)
  __shared__ float ps[260];
  __shared__ float sloc[20], qloc[20];
  int tid = threadIdx.x;
  int n = blockIdx.x;
  const float* xb = x + (size_t)n*9636;
  for (int i = tid; i < 22*452; i += 512){
    int h = i / 452, w = i - h*452;
    int gx = w - 6;
    xs[i] = (gx >= 0 && gx < 438) ? xb[h*438 + gx] : 0.f;
  }
  if (tid < 260) ps[tid] = pfx[tid];
  if (tid < 40){ if (tid < 20) sloc[tid] = 0.f; else qloc[tid-20] = 0.f; }
  __syncthreads();
  int wave = tid >> 6;
  int dg = __builtin_amdgcn_readfirstlane(wave >> 1);  // 0..3, wave-uniform
  int ct = tid & 127;                                  // column-thread within pair
  bool act = ct < 110;
  int c0 = act ? ct*4 : 0;                             // clamp (no LDS OOB)
  float acc[5][4];
  #pragma unroll
  for (int dl = 0; dl < 5; ++dl)
    #pragma unroll
    for (int j = 0; j < 4; ++j) acc[dl][j] = 0.f;
  const float* wb = weff2 + dg*1320;                   // [22][5][12] per dg
  #pragma unroll 1
  for (int h = 0; h < 22; ++h){
    const float4* xr = (const float4*)&xs[h*452 + c0];
    float4 v0 = xr[0], v1 = xr[1], v2 = xr[2], v3 = xr[3];
    float xw[16] = {v0.x,v0.y,v0.z,v0.w, v1.x,v1.y,v1.z,v1.w,
                    v2.x,v2.y,v2.z,v2.w, v3.x,v3.y,v3.z,v3.w};
    const float* wp = wb + h*60;                       // 60 contiguous, uniform
    #pragma unroll
    for (int dl = 0; dl < 5; ++dl){
      #pragma unroll
      for (int t = 0; t < 12; ++t){
        float w = wp[dl*12 + t];
        #pragma unroll
        for (int j = 0; j < 4; ++j)
          acc[dl][j] = fmaf(w, xw[t+j], acc[dl][j]);   // (h outer, t inner) = r3 order
      }
    }
  }
  float s5[5], q5[5];
  #pragma unroll
  for (int dl = 0; dl < 5; ++dl){ s5[dl] = 0.f; q5[dl] = 0.f; }
  if (act){
    #pragma unroll
    for (int dl = 0; dl < 5; ++dl){
      int d = dg*5 + dl;
      float* yb = y2 + (size_t)n*8780 + (size_t)d*439;
      #pragma unroll
      for (int j = 0; j < 4; ++j){
        int gw = c0 + j;
        if (gw < 439){
          int lo = 6 - gw; if (lo < 0) lo = 0;
          int hi = 444 - gw; if (hi > 12) hi = 12;
          float val = acc[dl][j] + (ps[d*13 + hi] - ps[d*13 + lo]);  // exact pad bias
          yb[gw] = val;
          s5[dl] += val; q5[dl] = fmaf(val, val, q5[dl]);
        }
      }
    }
  }
  #pragma unroll
  for (int off = 32; off; off >>= 1){
    #pragma unroll
    for (int dl = 0; dl < 5; ++dl){
      s5[dl] += __shfl_down(s5[dl], off);
      q5[dl] += __shfl_down(q5[dl], off);
    }
  }
  if ((tid & 63) == 0){
    #pragma unroll
    for (int dl = 0; dl < 5; ++dl){
      atomicAdd(&sloc[dg*5 + dl], s5[dl]);
      atomicAdd(&qloc[dg*5 + dl], q5[dl]);
    }
  }
  __syncthreads();
  if (tid < 20){
    atomicAdd(&st[ST_Y2S + tid], sloc[tid]);
    atomicAdd(&st[ST_Y2Q + tid], qloc[tid]);
  }
}

// ---------------- K4: covariance + Q/K/V congruence (patch-split LDS, float4 dots) ------
__global__ __launch_bounds__(256) void k4_cov_qkv(const float* __restrict__ y2, const float* __restrict__ st,
    const float* __restrict__ g2, const float* __restrict__ Wq, const float* __restrict__ Wk,
    const float* __restrict__ Wv, float* __restrict__ qkv){
  __shared__ __align__(16) float ysp[3][20][148];  // patch-split, zero-padded to 148
  __shared__ float a2s[20];
  __shared__ __align__(16) float Bt[3][18][20];    // [wt][i][d] = a2[d]*W[d][i]
  __shared__ __align__(16) float G3[3][400];
  __shared__ __align__(16) float Tmt[3][360];      // [m][jj*20+p]
  __shared__ float musum3[3][20];
  __shared__ float rtr3[3];
  int tid = threadIdx.x, n = blockIdx.x;
  if (tid < 20){
    const float invN = 1.f/(2048.f*439.f);
    float s = st[ST_Y2S + tid]*invN;
    float q = st[ST_Y2Q + tid]*invN;
    a2s[tid] = g2[tid] * rsqrtf(q - s*s + 1e-5f);
  }
  const float* yb = y2 + (size_t)n*8780;
  for (int i = tid; i < 8780; i += 256){
    int d = i/439, w = i - d*439;
    int m = (w >= 293) ? 2 : ((w >= 147) ? 1 : 0);
    int lw = w - ((m == 2) ? 293 : ((m == 1) ? 147 : 0));
    ysp[m][d][lw] = yb[i];
  }
  if (tid < 100){   // zero the pad slots
    int d = tid/5, k = tid - d*5;
    int m = (k == 0) ? 0 : ((k < 3) ? 1 : 2);
    int lw = (k == 0) ? 147 : ((k == 1 || k == 3) ? 146 : 147);
    ysp[m][d][lw] = 0.f;
  }
  __syncthreads();
  for (int i = tid; i < 1140; i += 256){
    if (i < 1080){
      int wt = i/360, r = i - wt*360; int d = r/18, jj = r - d*18;
      const float* Wm = (wt==0) ? Wq : ((wt==1) ? Wk : Wv);
      Bt[wt][jj][d] = a2s[d]*Wm[d*18 + jj];
    } else {
      int t = i - 1080; int m = t/20, d = t - m*20;
      const float4* r = (const float4*)&ysp[m][d][0];
      float4 acc = {0.f,0.f,0.f,0.f};
      #pragma unroll 1
      for (int w = 0; w < 37; ++w){ float4 v = r[w]; acc.x+=v.x; acc.y+=v.y; acc.z+=v.z; acc.w+=v.w; }
      musum3[m][d] = acc.x+acc.y+acc.z+acc.w;
    }
  }
  __syncthreads();
  for (int it = tid; it < 630; it += 256){
    int m = it/210, t = it - m*210;
    int rem = t, c = 0;
    while (rem >= 20 - c){ rem -= 20 - c; ++c; }
    int d = c + rem;
    const float4* ra = (const float4*)&ysp[m][c][0];
    const float4* rb = (const float4*)&ysp[m][d][0];
    float4 acc4 = {0.f,0.f,0.f,0.f};
    #pragma unroll 1
    for (int w = 0; w < 37; ++w){
      float4 a = ra[w], b = rb[w];
      acc4.x = fmaf(a.x,b.x,acc4.x); acc4.y = fmaf(a.y,b.y,acc4.y);
      acc4.z = fmaf(a.z,b.z,acc4.z); acc4.w = fmaf(a.w,b.w,acc4.w);
    }
    float invL = (m == 0) ? (1.f/147.f) : (1.f/146.f);
    float acc = (acc4.x+acc4.y+acc4.z+acc4.w) - musum3[m][c]*musum3[m][d]*invL;
    G3[m][c*20 + d] = acc; G3[m][d*20 + c] = acc;
  }
  __syncthreads();
  for (int wt = 0; wt < 3; ++wt){
    for (int i = tid; i < 1083; i += 256){
      if (i < 1080){
        int m = i/360, r = i - m*360; int p = r/18, jj = r - p*18;
        const float4* gr = (const float4*)&G3[m][p*20];
        const float4* br = (const float4*)&Bt[wt][jj][0];
        float4 a4 = {0.f,0.f,0.f,0.f};
        #pragma unroll
        for (int w = 0; w < 5; ++w){
          float4 a = gr[w], b = br[w];
          a4.x = fmaf(a.x,b.x,a4.x); a4.y = fmaf(a.y,b.y,a4.y);
          a4.z = fmaf(a.z,b.z,a4.z); a4.w = fmaf(a.w,b.w,a4.w);
        }
        Tmt[m][jj*20 + p] = a4.x+a4.y+a4.z+a4.w;
      } else if (wt == 0){
        int m = i - 1080;
        float tr = 0.f;
        for (int c = 0; c < 20; ++c){ float a = a2s[c]; tr = fmaf(a*a, G3[m][c*21], tr); }
        rtr3[m] = 1.f/tr;
      }
    }
    __syncthreads();
    for (int it = tid; it < 513; it += 256){
      int m = it/171, t = it - m*171;
      int rem = t, i = 0;
      while (rem >= 18 - i){ rem -= 18 - i; ++i; }
      int jj = i + rem;
      const float4* br = (const float4*)&Bt[wt][i][0];
      const float4* tr = (const float4*)&Tmt[m][jj*20];
      float4 a4 = {0.f,0.f,0.f,0.f};
      #pragma unroll
      for (int w = 0; w < 5; ++w){
        float4 a = br[w], b = tr[w];
        a4.x = fmaf(a.x,b.x,a4.x); a4.y = fmaf(a.y,b.y,a4.y);
        a4.z = fmaf(a.z,b.z,a4.z); a4.w = fmaf(a.w,b.w,a4.w);
      }
      float acc = (a4.x+a4.y+a4.z+a4.w) * rtr3[m];
      if (i == jj) acc += 1e-5f;
      float* outm = qkv + ((size_t)wt*6144 + (size_t)n*3 + m)*324;
      outm[i*18 + jj] = acc; outm[jj*18 + i] = acc;
    }
    __syncthreads();
  }
}

// ---------------- K5: batched 18x18 one-sided (Hestenes) Jacobi ----------------
// B = A (PSD; mode 1 input pre-shifted by SHIFT*I). Columns orthogonalize;
// b_i -> lam_i*u_i. 19 DS ops/round. (c,s) bitwise-identical on both partner
// lanes. mode 0: dst = U log(S) U^T. mode 1: fused triu-GEMV -> outp.
__global__ __launch_bounds__(256, 4) void k5_oneside(const float* __restrict__ src, float* __restrict__ dst,
    int nmat, int mode, const float* __restrict__ Wl, const float* __restrict__ bl,
    float* __restrict__ outp){
  __shared__ __align__(16) float stage[12][384];
  __shared__ __align__(16) float wls[2052];
  __shared__ float outacc[4][4];
  int tid = threadIdx.x;
  int wave = tid >> 6, lane = tid & 63;
  int g = (lane >= 54) ? 3 : (lane >= 36 ? 2 : (lane >= 18 ? 1 : 0));
  int j = lane - g*18;
  int gb = g*18;
  int slot = wave*3 + ((g < 3) ? g : 0);
  int mat = blockIdx.x*12 + wave*3 + g;
  bool act = (g < 3) && (mat < nmat);

  if (mode == 1){
    for (int i = tid; i < 2052; i += 256) wls[i] = Wl[i];
    if (tid < 16) outacc[tid >> 2][tid & 3] = 0.f;
  }

  float b[18];
  float sh = (mode == 1) ? SHIFT : 0.f;
  if (act){
    const float* s = src + (size_t)mat*324 + j*18;
    #pragma unroll
    for (int i = 0; i < 18; ++i) b[i] = s[i] + ((i == j) ? sh : 0.f);
  } else {
    #pragma unroll
    for (int i = 0; i < 18; ++i) b[i] = (i == j) ? 1.f : 0.f;
  }
  float nrm;
  { float n0 = 0.f, n1 = 0.f;
    #pragma unroll
    for (int k = 0; k < 18; k += 2){ n0 = fmaf(b[k],b[k],n0); n1 = fmaf(b[k+1],b[k+1],n1); }
    nrm = n0 + n1; }

  #pragma unroll 1
  for (int sweep = 0; sweep < NSWEEP; ++sweep){
    #pragma unroll
    for (int r = 0; r < 17; ++r){
      int xx = j - 1 - r; if (xx < 0) xx += 17;
      int v = r + 17 - xx; if (v >= 17) v -= 17;
      int m = (j == 0) ? (1 + r) : ((xx == 0) ? 0 : (1 + v));
      bool isp = (j == 0) ? true : ((xx == 0) ? false : (xx <= 8));
      int plane = (gb + m) & 63;
      float rv[18];
      #pragma unroll
      for (int k = 0; k < 18; ++k) rv[k] = __shfl(b[k], plane);
      float on = __shfl(nrm, plane);
      float g0 = 0.f, g1 = 0.f;
      #pragma unroll
      for (int k = 0; k < 18; k += 2){ g0 = fmaf(b[k], rv[k], g0); g1 = fmaf(b[k+1], rv[k+1], g1); }
      float gam = g0 + g1;                        // bitwise equal on both lanes
      float alpha = isp ? nrm : on;
      float beta  = isp ? on  : nrm;
      float tau = (beta - alpha) * 0.5f * __builtin_amdgcn_rcpf(gam);
      float tt = __builtin_amdgcn_rcpf(fabsf(tau) + sqrtf(fmaf(tau, tau, 1.f)));
      float t = (tau >= 0.f) ? tt : -tt;
      if (!(fabsf(gam) > 1e-36f)) t = 0.f;
      float c = __builtin_amdgcn_rsqf(fmaf(t, t, 1.f));
      float s = t*c;
      nrm = fmaf(isp ? -t : t, gam, nrm);
      float sg = isp ? -s : s;
      #pragma unroll
      for (int k = 0; k < 18; ++k) b[k] = fmaf(c, b[k], sg*rv[k]);
    }
  }
  float n0 = 0.f, n1 = 0.f;
  #pragma unroll
  for (int k = 0; k < 18; k += 2){ n0 = fmaf(b[k],b[k],n0); n1 = fmaf(b[k+1],b[k+1],n1); }
  float nf = fmaxf(n0 + n1, 1e-30f);
  float fv = (mode == 0) ? (0.5f * logf(nf)) : fmaxf(sqrtf(nf) - SHIFT, LOGEPS);
  float wv = fv * __builtin_amdgcn_rcpf(nf);
  float* sp = &stage[slot][0];
  if (act){
    #pragma unroll
    for (int k = 0; k < 18; ++k) sp[k*20 + j] = b[k];
    sp[360 + j] = wv;
  }
  __syncthreads();
  if (act){
    float wr[18];
    #pragma unroll
    for (int i = 0; i < 18; ++i) wr[i] = sp[j*20 + i] * sp[360 + i];
    float frow[18];
    #pragma unroll
    for (int i2 = 0; i2 < 18; ++i2){
      const float* br = &sp[i2*20];
      float a0 = 0.f;
      #pragma unroll
      for (int k = 0; k < 16; k += 4){
        float4 v4 = *(const float4*)&br[k];
        a0 = fmaf(wr[k],   v4.x, a0); a0 = fmaf(wr[k+1], v4.y, a0);
        a0 = fmaf(wr[k+2], v4.z, a0); a0 = fmaf(wr[k+3], v4.w, a0);
      }
      a0 = fmaf(wr[16], br[16], a0);
      a0 = fmaf(wr[17], br[17], a0);
      frow[i2] = a0;
    }
    if (mode == 0){
      float* orow = dst + (size_t)mat*324 + j*18;
      #pragma unroll
      for (int i2 = 0; i2 < 18; ++i2) orow[i2] = frow[i2];
    } else {
      int base = (g*171 + j*(37 - j)/2 - j)*4;
      float o0=0.f, o1=0.f, o2=0.f, o3=0.f;
      #pragma unroll
      for (int jj = 0; jj < 18; ++jj){
        if (jj >= j){
          const float* w4 = &wls[base + jj*4];
          o0 = fmaf(frow[jj], w4[0], o0);
          o1 = fmaf(frow[jj], w4[1], o1);
          o2 = fmaf(frow[jj], w4[2], o2);
          o3 = fmaf(frow[jj], w4[3], o3);
        }
      }
      atomicAdd(&outacc[wave][0], o0);
      atomicAdd(&outacc[wave][1], o1);
      atomicAdd(&outacc[wave][2], o2);
      atomicAdd(&outacc[wave][3], o3);
    }
  }
  if (mode == 1){
    __syncthreads();
    if (tid < 16){
      int bi = tid >> 2, o = tid & 3;
      outp[(blockIdx.x*4 + bi)*4 + o] = outacc[bi][o] + bl[o];
    }
  }
}

// ---------------- K6: energies -> scores -> softmax -> mixed (shuffle-reduced) --------
__global__ __launch_bounds__(128) void k6_attnmix(const float* __restrict__ logs, float* __restrict__ mixed){
  __shared__ float lq[972], lk[972], lv[972];
  __shared__ float ew[2][9];
  __shared__ float P[9];
  int b = blockIdx.x, tid = threadIdx.x;
  const float* q  = logs + (size_t)b*972;
  const float* k_ = logs + 1990656 + (size_t)b*972;
  const float* v_ = logs + 3981312 + (size_t)b*972;
  for (int i = tid; i < 972; i += 128){ lq[i] = q[i]; lk[i] = k_[i]; lv[i] = v_[i]; }
  __syncthreads();
  float e[9] = {0.f,0.f,0.f,0.f,0.f,0.f,0.f,0.f,0.f};
  for (int x = tid; x < 324; x += 128){
    float q0 = lq[x], q1 = lq[324+x], q2 = lq[648+x];
    float k0 = lk[x], k1 = lk[324+x], k2 = lk[648+x];
    float d;
    d = q0-k0; e[0] = fmaf(d,d,e[0]);
    d = q0-k1; e[1] = fmaf(d,d,e[1]);
    d = q0-k2; e[2] = fmaf(d,d,e[2]);
    d = q1-k0; e[3] = fmaf(d,d,e[3]);
    d = q1-k1; e[4] = fmaf(d,d,e[4]);
    d = q1-k2; e[5] = fmaf(d,d,e[5]);
    d = q2-k0; e[6] = fmaf(d,d,e[6]);
    d = q2-k1; e[7] = fmaf(d,d,e[7]);
    d = q2-k2; e[8] = fmaf(d,d,e[8]);
  }
  #pragma unroll
  for (int p = 0; p < 9; ++p)
    for (int off = 32; off; off >>= 1) e[p] += __shfl_down(e[p], off);
  if ((tid & 63) == 0){
    #pragma unroll
    for (int p = 0; p < 9; ++p) ew[tid >> 6][p] = e[p];
  }
  __syncthreads();
  if (tid < 3){
    float en0 = ew[0][tid*3+0] + ew[1][tid*3+0];
    float en1 = ew[0][tid*3+1] + ew[1][tid*3+1];
    float en2 = ew[0][tid*3+2] + ew[1][tid*3+2];
    float s0 = 1.f/(1.f + log1pf(en0));
    float s1 = 1.f/(1.f + log1pf(en1));
    float s2 = 1.f/(1.f + log1pf(en2));
    float mx = fmaxf(s0, fmaxf(s1, s2));
    float e0 = expf(s0-mx), e1 = expf(s1-mx), e2 = expf(s2-mx);
    float inv = 1.f/(e0+e1+e2);
    P[tid*3+0] = e0*inv; P[tid*3+1] = e1*inv; P[tid*3+2] = e2*inv;
  }
  __syncthreads();
  float p00=P[0],p01=P[1],p02=P[2],p10=P[3],p11=P[4],p12=P[5],p20=P[6],p21=P[7],p22=P[8];
  float* mb = mixed + (size_t)b*972;
  for (int x = tid; x < 324; x += 128){
    float v0 = lv[x], v1 = lv[324+x], v2 = lv[648+x];
    mb[x]     = p00*v0 + p01*v1 + p02*v2;
    mb[324+x] = p10*v0 + p11*v1 + p12*v2;
    mb[648+x] = p20*v0 + p21*v1 + p22*v2;
  }
}

// ---------------- launcher ----------------
extern "C" void kernel_launch(void* const* d_in, const int* in_sizes, int n_in,
                              void* d_out, int out_size, void* d_ws, size_t ws_size,
                              hipStream_t stream){
  (void)in_sizes; (void)n_in; (void)out_size; (void)ws_size;
  const float* x   = (const float*)d_in[0];
  const float* W1  = (const float*)d_in[1];
  const float* g1  = (const float*)d_in[3];
  const float* be1 = (const float*)d_in[4];
  const float* W2  = (const float*)d_in[5];
  const float* g2  = (const float*)d_in[7];
  const float* Wq  = (const float*)d_in[9];
  const float* Wk  = (const float*)d_in[10];
  const float* Wv  = (const float*)d_in[11];
  const float* Wl  = (const float*)d_in[12];
  const float* bl  = (const float*)d_in[13];
  float* ws    = (float*)d_ws;
  float* y2    = ws + OFF_Y2;
  float* qkv   = ws + OFF_QKV;
  float* weff2 = ws + OFF_QKV;          // overlay: qkv region free until k4
  float* pfx   = ws + OFF_QKV + 5280;
  float* logs  = ws + OFF_Y2;    // overlay: y2 dead after k4
  float* mixed = ws + OFF_QKV;   // overlay: qkv dead after k5#1
  float* st    = ws + OFF_ST;
  float* outp  = (float*)d_out;

  k0_zero    <<<dim3(1),       dim3(256), 0, stream>>>(st);
  k1_xstats  <<<dim3(2048),    dim3(256), 0, stream>>>(x, st);
  k1b_fold   <<<dim3(1),       dim3(64),  0, stream>>>(W1, g1, be1, st);
  k2_weff    <<<dim3(1),       dim3(256), 0, stream>>>(W2, st, weff2, pfx);
  k3_conv    <<<dim3(2048),    dim3(512), 0, stream>>>(x, weff2, pfx, st, y2);
  k4_cov_qkv <<<dim3(2048),    dim3(256), 0, stream>>>(y2, st, g2, Wq, Wk, Wv, qkv);
  k5_oneside <<<dim3(1536),    dim3(256), 0, stream>>>(qkv, logs, 18432, 0, nullptr, nullptr, nullptr);
  k6_attnmix <<<dim3(2048),    dim3(128), 0, stream>>>(logs, mixed);
  k5_oneside <<<dim3(512),     dim3(256), 0, stream>>>(mixed, nullptr, 6144, 1, Wl, bl, outp);
}